// Round 1
// 1630.206 us; speedup vs baseline: 1.0679x; 1.0679x over previous
//
#include <hip/hip_runtime.h>

#define NS 8
#define ML 4096
#define HD 1024
#define K2 2048
#define NEV 32768
#define NLEV 12
#define NE 16384
#define NSLOT (NS * ML)
#define CAP 8
#define BK 64
#define NT (K2 / BK)          // 32 K-tiles
#define LDS_BYTES 131072      // 2 dbuf x (A 32KB + B 32KB)

typedef __attribute__((ext_vector_type(8))) short bf16x8;
typedef __attribute__((ext_vector_type(4))) float f32x4;

typedef __attribute__((address_space(1))) const void cvoid_g;
typedef __attribute__((address_space(3))) void void_l;

static __device__ __forceinline__ void load_lds_16(const void* g, void* l) {
    __builtin_amdgcn_global_load_lds((cvoid_g*)g, (void_l*)l, 16, 0, 0);
}

static __device__ __forceinline__ unsigned short f2bf(float f) {
    unsigned u = __float_as_uint(f);
    unsigned r = (u + 0x7fffu + ((u >> 16) & 1u)) >> 16;
    return (unsigned short)r;
}

static __device__ __forceinline__ float fast_tanh(float x) {
    return 1.0f - 2.0f / (__expf(2.0f * x) + 1.0f);
}

// ---- W [2048][1024] f32 -> WbT [1024][2048] bf16 (transposed) ----
__global__ void wt_kernel(const float* __restrict__ W, unsigned short* __restrict__ WbT) {
    __shared__ unsigned short tile[64][65];
    const int t = threadIdx.x;
    const int k0 = blockIdx.x * 64;
    const int n0 = blockIdx.y * 64;
#pragma unroll
    for (int i = 0; i < 16; i++) {
        int idx = i * 256 + t;
        int r = idx >> 6, c = idx & 63;
        tile[r][c] = f2bf(W[(size_t)(k0 + r) * HD + n0 + c]);
    }
    __syncthreads();
#pragma unroll
    for (int i = 0; i < 16; i++) {
        int idx = i * 256 + t;
        int r = idx >> 6, c = idx & 63;
        WbT[(size_t)(n0 + r) * K2 + k0 + c] = tile[c][r];
    }
}

// ---- char dedupe pass 1 ----
__global__ void char_ticket(const int* __restrict__ cseq, const int* __restrict__ cpos,
                            int* __restrict__ counts, int* __restrict__ ticket,
                            int* __restrict__ evlist) {
    const int e = blockIdx.x * 256 + threadIdx.x;
    if (e >= NEV) return;
    const int slot = cseq[e] * ML + cpos[e];
    const int t = atomicAdd(&counts[slot], 1);
    ticket[e] = t;
    if (t < CAP) evlist[slot * CAP + t] = e;
}

// ---- char dedupe pass 2: plain store, zero-fills empty slots ----
__global__ void char_slot_sum(const int* __restrict__ counts, const int* __restrict__ evlist,
                              const int* __restrict__ cid, const float* __restrict__ emb,
                              float* __restrict__ h) {
    const int slot = blockIdx.x;
    const int t = threadIdx.x;
    int n = counts[slot];
    if (n > CAP) n = CAP;
    float4 acc = {0.f, 0.f, 0.f, 0.f};
    for (int i = 0; i < n; i++) {
        const int e = evlist[slot * CAP + i];
        const int id = cid[e];
        const float4 v = ((const float4*)(emb + (size_t)id * HD))[t];
        acc.x += v.x; acc.y += v.y; acc.z += v.z; acc.w += v.w;
    }
    ((float4*)(h + (size_t)slot * HD))[t] = acc;
}

// ---- char overflow fallback ----
__global__ void char_overflow(const int* __restrict__ cseq, const int* __restrict__ cpos,
                              const int* __restrict__ cid, const int* __restrict__ ticket,
                              const float* __restrict__ emb, float* __restrict__ h) {
    const int e0 = blockIdx.x * 128;
    const int t = threadIdx.x;
    for (int i = 0; i < 128; i++) {
        const int e = e0 + i;
        if (ticket[e] < CAP) continue;
        const int slot = cseq[e] * ML + cpos[e];
        const int id = cid[e];
        const float4 v = ((const float4*)(emb + (size_t)id * HD))[t];
        float* dst = h + (size_t)slot * HD + t * 4;
        atomicAdd(dst + 0, v.x);
        atomicAdd(dst + 1, v.y);
        atomicAdd(dst + 2, v.z);
        atomicAdd(dst + 3, v.w);
    }
}

// ---- group-event dup detection (all 12 levels at once; indices are static) ----
__global__ void grp_count(const int* __restrict__ iseq, const int* __restrict__ ipos,
                          int* __restrict__ gcounts) {
    const int idx = blockIdx.x * 256 + threadIdx.x;   // 12*16384
    if (idx >= NLEV * NE) return;
    const int lev = idx >> 14;
    atomicAdd(&gcounts[lev * NSLOT + iseq[idx] * ML + ipos[idx]], 1);
}

__global__ void grp_dup(const int* __restrict__ iseq, const int* __restrict__ ipos,
                        const int* __restrict__ gcounts, unsigned char* __restrict__ dup) {
    const int idx = blockIdx.x * 256 + threadIdx.x;
    if (idx >= NLEV * NE) return;
    const int lev = idx >> 14;
    dup[idx] = (gcounts[lev * NSLOT + iseq[idx] * ML + ipos[idx]] > 1) ? 1 : 0;
}

// ---- per-level gather ----
__global__ void gather_x(const float* __restrict__ h, const int* __restrict__ iseq,
                         const int* __restrict__ ifirst, const int* __restrict__ isecond,
                         unsigned short* __restrict__ X) {
    const int e = blockIdx.x;
    const int t = threadIdx.x;
    const int seq = iseq[e], f = ifirst[e], s = isecond[e];
    const float4 a = ((const float4*)(h + ((size_t)seq * ML + f) * HD))[t];
    const float4 b = ((const float4*)(h + ((size_t)seq * ML + s) * HD))[t];
    ushort4 pa, pb;
    pa.x = f2bf(a.x); pa.y = f2bf(a.y); pa.z = f2bf(a.z); pa.w = f2bf(a.w);
    pb.x = f2bf(b.x); pb.y = f2bf(b.y); pb.z = f2bf(b.z); pb.w = f2bf(b.w);
    *(ushort4*)(X + (size_t)e * K2 + t * 4) = pa;
    *(ushort4*)(X + (size_t)e * K2 + HD + t * 4) = pb;
}

// ---- fused GEMM + bias + tanh + dedupe'd scatter ----
// 256x256 tile, BK=64, 8 waves (2M x 4N), 128KB double-buffered LDS.
// Counted-vmcnt pipeline: raw s_barrier (no compiler vmcnt(0) drain); tile k+1's
// 8 global_load_lds stay in flight across the barrier; vmcnt(8) guarantees tile k
// landed (vmcnt retires oldest-first). Stage always targets the dbuf NOT being
// read this iteration, whose previous reads finished one barrier earlier -> no
// write/read race by construction. Proven xor-swizzle (byte ^= (row&7)<<4 at 16B
// granularity) on both stage-source and ds_read keeps bank conflicts at 0.
__global__ __launch_bounds__(512, 2) void gemm_scatter(
    const unsigned short* __restrict__ X,
    const unsigned short* __restrict__ WbT,
    const float* __restrict__ bias,
    const int* __restrict__ iseq, const int* __restrict__ ipos,
    const unsigned char* __restrict__ dup,
    float* __restrict__ h) {
    extern __shared__ unsigned short lds[];
    const int t = threadIdx.x;
    const int lane = t & 63;
    const int w = t >> 6;            // 0..7
    const int wm = w >> 2;           // 0..1  (M half: 128 rows each)
    const int wn = (w & 3) * 64;     // 0,64,128,192 (N quarter: 64 cols)
    const int fr = lane & 15, fq = lane >> 4;

    // bijective XCD swizzle: 256 blocks, 8 XCDs; each XCD's 32 blocks share one
    // 1MB B-panel (L2-resident) -> B stages are L2 hits.
    const int bid = blockIdx.x;
    const int xcd = bid & 7, bix = bid >> 3;
    const int row0 = ((xcd & 1) * 32 + bix) * 256;   // 64 row blocks
    const int col0 = (xcd >> 1) * 256;               // 4 col blocks

    // staging geometry: per tile, A = 2048 16B-chunks (256 rows x 8), B same.
    // thread t handles chunks c = i*512+t (i=0..3): row r = i*64 + (t>>3),
    // source chunk sp = (t&7) ^ (r&7) (xor-swizzle, self-inverse); LDS linear.
    const int tr = t >> 3;                           // 0..63
    const int sp = (t & 7) ^ (tr & 7);
    const unsigned short* Asrc = X + (size_t)(row0 + tr) * K2 + sp * 8;
    const unsigned short* Bsrc = WbT + (size_t)(col0 + tr) * K2 + sp * 8;

    f32x4 acc[8][4];
#pragma unroll
    for (int i = 0; i < 8; i++)
#pragma unroll
        for (int j = 0; j < 4; j++) acc[i][j] = (f32x4){0.f, 0.f, 0.f, 0.f};

    // prologue: stage tile 0 -> dbuf 0
    {
        unsigned short* dA = lds;
        unsigned short* dB = lds + 16384;
#pragma unroll
        for (int i = 0; i < 4; i++)
            load_lds_16(Asrc + (size_t)(i * 64) * K2, &dA[(i * 512 + t) * 8]);
#pragma unroll
        for (int i = 0; i < 4; i++)
            load_lds_16(Bsrc + (size_t)(i * 64) * K2, &dB[(i * 512 + t) * 8]);
    }

    for (int kt = 0; kt < NT; kt++) {
        const int d = kt & 1;
        if (kt + 1 < NT) {
            // stage tile kt+1 into the other dbuf (its old contents were last
            // read before the previous end-of-iteration barrier -> safe)
            unsigned short* dA = lds + (d ^ 1) * 32768;
            unsigned short* dB = dA + 16384;
            const size_t ko = (size_t)(kt + 1) * BK;
#pragma unroll
            for (int i = 0; i < 4; i++)
                load_lds_16(Asrc + (size_t)(i * 64) * K2 + ko, &dA[(i * 512 + t) * 8]);
#pragma unroll
            for (int i = 0; i < 4; i++)
                load_lds_16(Bsrc + (size_t)(i * 64) * K2 + ko, &dB[(i * 512 + t) * 8]);
            // wait for tile kt's 8 loads; keep tile kt+1's 8 in flight
            asm volatile("s_waitcnt vmcnt(8)" ::: "memory");
        } else {
            asm volatile("s_waitcnt vmcnt(0)" ::: "memory");
        }
        __builtin_amdgcn_s_barrier();
        asm volatile("" ::: "memory");

        const unsigned short* sA = lds + d * 32768;
        const unsigned short* sB = sA + 16384;
#pragma unroll
        for (int q = 0; q < 4; q++) {               // 4 quadrant phases x 16 MFMA
            const int mh = (q & 1) * 64;            // wave-local M half
            const int nh = (q >> 1) * 32;           // wave-local N half
            bf16x8 af[2][4], bfr[2][2];
#pragma unroll
            for (int ks = 0; ks < 2; ks++) {
                const int qs = ((ks * 4 + fq) ^ (fr & 7)) * 8;
#pragma unroll
                for (int mt = 0; mt < 4; mt++)
                    af[ks][mt] = *(const bf16x8*)&sA[(wm * 128 + mh + mt * 16 + fr) * BK + qs];
#pragma unroll
                for (int nt = 0; nt < 2; nt++)
                    bfr[ks][nt] = *(const bf16x8*)&sB[(wn + nh + nt * 16 + fr) * BK + qs];
            }
            __builtin_amdgcn_s_setprio(1);
#pragma unroll
            for (int ks = 0; ks < 2; ks++)
#pragma unroll
                for (int mt = 0; mt < 4; mt++)
#pragma unroll
                    for (int nt = 0; nt < 2; nt++)
                        acc[(q & 1) * 4 + mt][(q >> 1) * 2 + nt] =
                            __builtin_amdgcn_mfma_f32_16x16x32_bf16(
                                af[ks][mt], bfr[ks][nt],
                                acc[(q & 1) * 4 + mt][(q >> 1) * 2 + nt], 0, 0, 0);
            __builtin_amdgcn_s_setprio(0);
        }
        asm volatile("" ::: "memory");
        __builtin_amdgcn_s_barrier();   // all reads of dbuf d done before next stage into it
    }

    // epilogue: bias + tanh; sole-writer events use plain RMW, dups use atomics
    float bv[4];
#pragma unroll
    for (int ni = 0; ni < 4; ni++) bv[ni] = bias[col0 + wn + ni * 16 + fr];
#pragma unroll
    for (int mi = 0; mi < 8; mi++) {
#pragma unroll
        for (int r = 0; r < 4; r++) {
            const int e = row0 + wm * 128 + mi * 16 + fq * 4 + r;
            const int seq = iseq[e], pos = ipos[e];
            float* hrow = h + ((size_t)seq * ML + pos) * HD + col0 + wn;
            if (dup[e]) {
#pragma unroll
                for (int ni = 0; ni < 4; ni++) {
                    float x = fast_tanh(acc[mi][ni][r] + bv[ni]);
                    atomicAdd(&hrow[ni * 16 + fr], x);
                }
            } else {
#pragma unroll
                for (int ni = 0; ni < 4; ni++) {
                    float x = fast_tanh(acc[mi][ni][r] + bv[ni]);
                    hrow[ni * 16 + fr] += x;
                }
            }
        }
    }
}

// ---- final: h[:, 0, :] = 0 ----
__global__ void zero_first(float* __restrict__ h) {
    const int t = blockIdx.x * 256 + threadIdx.x;
    const int seq = t >> 10, d = t & 1023;
    h[(size_t)seq * ML * HD + d] = 0.0f;
}

extern "C" void kernel_launch(void* const* d_in, const int* in_sizes, int n_in,
                              void* d_out, int out_size, void* d_ws, size_t ws_size,
                              hipStream_t stream) {
    const int* char_i_seq = (const int*)d_in[0];
    const int* char_i_pos = (const int*)d_in[1];
    const int* char_ids   = (const int*)d_in[2];
    const int* grp_i_seq    = (const int*)d_in[3];
    const int* grp_i_first  = (const int*)d_in[4];
    const int* grp_i_second = (const int*)d_in[5];
    const int* grp_i_pos    = (const int*)d_in[6];
    const float* emb = (const float*)d_in[7];
    const float* W   = (const float*)d_in[8];
    const float* b   = (const float*)d_in[9];
    float* h = (float*)d_out;

    unsigned short* WbT = (unsigned short*)d_ws;                            // 4 MB @ 0
    unsigned short* X   = (unsigned short*)((char*)d_ws + (8u << 20));      // 64 MB @ 8M
    int* counts = (int*)((char*)d_ws + (72u << 20));                        // 128 KB
    int* ticket = (int*)((char*)d_ws + (72u << 20) + (1u << 18));           // 128 KB
    int* evlist = (int*)((char*)d_ws + (72u << 20) + (1u << 19));           // 1 MB
    int* gcounts = (int*)((char*)d_ws + (74u << 20));                       // 1.5 MB
    unsigned char* gdup = (unsigned char*)((char*)d_ws + (76u << 20));      // 192 KB

    static bool attr_done = false;
    if (!attr_done) {
        (void)hipFuncSetAttribute((const void*)gemm_scatter,
                                  hipFuncAttributeMaxDynamicSharedMemorySize, LDS_BYTES);
        attr_done = true;
    }

    hipMemsetAsync(counts, 0, NSLOT * sizeof(int), stream);
    hipMemsetAsync(gcounts, 0, (size_t)NLEV * NSLOT * sizeof(int), stream);
    wt_kernel<<<dim3(32, 16), 256, 0, stream>>>(W, WbT);
    char_ticket<<<NEV / 256, 256, 0, stream>>>(char_i_seq, char_i_pos, counts, ticket, evlist);
    char_slot_sum<<<NSLOT, 256, 0, stream>>>(counts, evlist, char_ids, emb, h);
    char_overflow<<<NEV / 128, 256, 0, stream>>>(char_i_seq, char_i_pos, char_ids, ticket, emb, h);
    grp_count<<<(NLEV * NE) / 256, 256, 0, stream>>>(grp_i_seq, grp_i_pos, gcounts);
    grp_dup<<<(NLEV * NE) / 256, 256, 0, stream>>>(grp_i_seq, grp_i_pos, gcounts, gdup);

    for (int lev = 0; lev < NLEV; lev++) {
        const int* iseq = grp_i_seq + lev * NE;
        const int* ifir = grp_i_first + lev * NE;
        const int* isec = grp_i_second + lev * NE;
        const int* ipos = grp_i_pos + lev * NE;
        gather_x<<<NE, 256, 0, stream>>>(h, iseq, ifir, isec, X);
        gemm_scatter<<<dim3(256), 512, LDS_BYTES, stream>>>(X, WbT, b, iseq, ipos,
                                                            gdup + lev * NE, h);
    }
    zero_first<<<32, 256, 0, stream>>>(h);
}

// Round 2
// 1578.360 us; speedup vs baseline: 1.1030x; 1.0328x over previous
//
#include <hip/hip_runtime.h>

#define NS 8
#define ML 4096
#define HD 1024
#define K2 2048
#define NEV 32768
#define NLEV 12
#define NE 16384
#define NSLOT (NS * ML)
#define CAP 8
#define BK 64
#define NT (K2 / BK)          // 32 K-tiles
#define LDS_BYTES 131072      // 2 dbuf x (A 32KB + B 32KB)

typedef __attribute__((ext_vector_type(8))) short bf16x8;
typedef __attribute__((ext_vector_type(4))) float f32x4;

typedef __attribute__((address_space(1))) const void cvoid_g;
typedef __attribute__((address_space(3))) void void_l;

static __device__ __forceinline__ void load_lds_16(const void* g, void* l) {
    __builtin_amdgcn_global_load_lds((cvoid_g*)g, (void_l*)l, 16, 0, 0);
}

static __device__ __forceinline__ unsigned short f2bf(float f) {
    unsigned u = __float_as_uint(f);
    unsigned r = (u + 0x7fffu + ((u >> 16) & 1u)) >> 16;
    return (unsigned short)r;
}

static __device__ __forceinline__ float fast_tanh(float x) {
    return 1.0f - 2.0f / (__expf(2.0f * x) + 1.0f);
}

// ---- W [2048][1024] f32 -> WbT [1024][2048] bf16 (transposed) ----
__global__ void wt_kernel(const float* __restrict__ W, unsigned short* __restrict__ WbT) {
    __shared__ unsigned short tile[64][65];
    const int t = threadIdx.x;
    const int k0 = blockIdx.x * 64;
    const int n0 = blockIdx.y * 64;
#pragma unroll
    for (int i = 0; i < 16; i++) {
        int idx = i * 256 + t;
        int r = idx >> 6, c = idx & 63;
        tile[r][c] = f2bf(W[(size_t)(k0 + r) * HD + n0 + c]);
    }
    __syncthreads();
#pragma unroll
    for (int i = 0; i < 16; i++) {
        int idx = i * 256 + t;
        int r = idx >> 6, c = idx & 63;
        WbT[(size_t)(n0 + r) * K2 + k0 + c] = tile[c][r];
    }
}

// ---- char dedupe pass 1 ----
__global__ void char_ticket(const int* __restrict__ cseq, const int* __restrict__ cpos,
                            int* __restrict__ counts, int* __restrict__ ticket,
                            int* __restrict__ evlist) {
    const int e = blockIdx.x * 256 + threadIdx.x;
    if (e >= NEV) return;
    const int slot = cseq[e] * ML + cpos[e];
    const int t = atomicAdd(&counts[slot], 1);
    ticket[e] = t;
    if (t < CAP) evlist[slot * CAP + t] = e;
}

// ---- char dedupe pass 2: plain store, zero-fills empty slots ----
__global__ void char_slot_sum(const int* __restrict__ counts, const int* __restrict__ evlist,
                              const int* __restrict__ cid, const float* __restrict__ emb,
                              float* __restrict__ h) {
    const int slot = blockIdx.x;
    const int t = threadIdx.x;
    int n = counts[slot];
    if (n > CAP) n = CAP;
    float4 acc = {0.f, 0.f, 0.f, 0.f};
    for (int i = 0; i < n; i++) {
        const int e = evlist[slot * CAP + i];
        const int id = cid[e];
        const float4 v = ((const float4*)(emb + (size_t)id * HD))[t];
        acc.x += v.x; acc.y += v.y; acc.z += v.z; acc.w += v.w;
    }
    ((float4*)(h + (size_t)slot * HD))[t] = acc;
}

// ---- char overflow fallback ----
__global__ void char_overflow(const int* __restrict__ cseq, const int* __restrict__ cpos,
                              const int* __restrict__ cid, const int* __restrict__ ticket,
                              const float* __restrict__ emb, float* __restrict__ h) {
    const int e0 = blockIdx.x * 128;
    const int t = threadIdx.x;
    for (int i = 0; i < 128; i++) {
        const int e = e0 + i;
        if (ticket[e] < CAP) continue;
        const int slot = cseq[e] * ML + cpos[e];
        const int id = cid[e];
        const float4 v = ((const float4*)(emb + (size_t)id * HD))[t];
        float* dst = h + (size_t)slot * HD + t * 4;
        atomicAdd(dst + 0, v.x);
        atomicAdd(dst + 1, v.y);
        atomicAdd(dst + 2, v.z);
        atomicAdd(dst + 3, v.w);
    }
}

// ---- group-event dup detection (all 12 levels at once; indices are static) ----
__global__ void grp_count(const int* __restrict__ iseq, const int* __restrict__ ipos,
                          int* __restrict__ gcounts) {
    const int idx = blockIdx.x * 256 + threadIdx.x;   // 12*16384
    if (idx >= NLEV * NE) return;
    const int lev = idx >> 14;
    atomicAdd(&gcounts[lev * NSLOT + iseq[idx] * ML + ipos[idx]], 1);
}

__global__ void grp_dup(const int* __restrict__ iseq, const int* __restrict__ ipos,
                        const int* __restrict__ gcounts, unsigned char* __restrict__ dup) {
    const int idx = blockIdx.x * 256 + threadIdx.x;
    if (idx >= NLEV * NE) return;
    const int lev = idx >> 14;
    dup[idx] = (gcounts[lev * NSLOT + iseq[idx] * ML + ipos[idx]] > 1) ? 1 : 0;
}

// ---- per-level gather ----
__global__ void gather_x(const float* __restrict__ h, const int* __restrict__ iseq,
                         const int* __restrict__ ifirst, const int* __restrict__ isecond,
                         unsigned short* __restrict__ X) {
    const int e = blockIdx.x;
    const int t = threadIdx.x;
    const int seq = iseq[e], f = ifirst[e], s = isecond[e];
    const float4 a = ((const float4*)(h + ((size_t)seq * ML + f) * HD))[t];
    const float4 b = ((const float4*)(h + ((size_t)seq * ML + s) * HD))[t];
    ushort4 pa, pb;
    pa.x = f2bf(a.x); pa.y = f2bf(a.y); pa.z = f2bf(a.z); pa.w = f2bf(a.w);
    pb.x = f2bf(b.x); pb.y = f2bf(b.y); pb.z = f2bf(b.z); pb.w = f2bf(b.w);
    *(ushort4*)(X + (size_t)e * K2 + t * 4) = pa;
    *(ushort4*)(X + (size_t)e * K2 + HD + t * 4) = pb;
}

// ---- fused GEMM + bias + tanh + dedupe'd scatter ----
// 256x256 tile, BK=64, 8 waves (2M x 4N), 128KB double-buffered LDS.
// Counted-vmcnt pipeline (round 1) + ks-outer fragment reuse (round 2):
// per K-half read 8 A-frags + 4 B-frags ONCE (12 ds_read_b128) and run the
// full 32-MFMA outer product. 24 b128/wave/K-tile (minimal) vs 48 before ->
// LDS read traffic 384KB -> 192KB per CU per K-tile, back under the MFMA cost.
__global__ __launch_bounds__(512, 2) void gemm_scatter(
    const unsigned short* __restrict__ X,
    const unsigned short* __restrict__ WbT,
    const float* __restrict__ bias,
    const int* __restrict__ iseq, const int* __restrict__ ipos,
    const unsigned char* __restrict__ dup,
    float* __restrict__ h) {
    extern __shared__ unsigned short lds[];
    const int t = threadIdx.x;
    const int lane = t & 63;
    const int w = t >> 6;            // 0..7
    const int wm = w >> 2;           // 0..1  (M half: 128 rows each)
    const int wn = (w & 3) * 64;     // 0,64,128,192 (N quarter: 64 cols)
    const int fr = lane & 15, fq = lane >> 4;

    // bijective XCD swizzle: 256 blocks, 8 XCDs; each XCD's 32 blocks share one
    // B-panel (L2-resident) -> B stages are L2 hits.
    const int bid = blockIdx.x;
    const int xcd = bid & 7, bix = bid >> 3;
    const int row0 = ((xcd & 1) * 32 + bix) * 256;   // 64 row blocks
    const int col0 = (xcd >> 1) * 256;               // 4 col blocks

    // staging geometry: per tile, A = 2048 16B-chunks (256 rows x 8), B same.
    // thread t handles chunks c = i*512+t (i=0..3): row r = i*64 + (t>>3),
    // source chunk sp = (t&7) ^ (r&7) (xor-swizzle, self-inverse); LDS linear.
    const int tr = t >> 3;                           // 0..63
    const int sp = (t & 7) ^ (tr & 7);
    const unsigned short* Asrc = X + (size_t)(row0 + tr) * K2 + sp * 8;
    const unsigned short* Bsrc = WbT + (size_t)(col0 + tr) * K2 + sp * 8;

    f32x4 acc[8][4];
#pragma unroll
    for (int i = 0; i < 8; i++)
#pragma unroll
        for (int j = 0; j < 4; j++) acc[i][j] = (f32x4){0.f, 0.f, 0.f, 0.f};

    // prologue: stage tile 0 -> dbuf 0
    {
        unsigned short* dA = lds;
        unsigned short* dB = lds + 16384;
#pragma unroll
        for (int i = 0; i < 4; i++)
            load_lds_16(Asrc + (size_t)(i * 64) * K2, &dA[(i * 512 + t) * 8]);
#pragma unroll
        for (int i = 0; i < 4; i++)
            load_lds_16(Bsrc + (size_t)(i * 64) * K2, &dB[(i * 512 + t) * 8]);
    }

    for (int kt = 0; kt < NT; kt++) {
        const int d = kt & 1;
        if (kt + 1 < NT) {
            // stage tile kt+1 into the other dbuf (its old contents were last
            // read before the previous end-of-iteration barrier -> safe)
            unsigned short* dA = lds + (d ^ 1) * 32768;
            unsigned short* dB = dA + 16384;
            const size_t ko = (size_t)(kt + 1) * BK;
#pragma unroll
            for (int i = 0; i < 4; i++)
                load_lds_16(Asrc + (size_t)(i * 64) * K2 + ko, &dA[(i * 512 + t) * 8]);
#pragma unroll
            for (int i = 0; i < 4; i++)
                load_lds_16(Bsrc + (size_t)(i * 64) * K2 + ko, &dB[(i * 512 + t) * 8]);
            // wait for tile kt's 8 loads; keep tile kt+1's 8 in flight
            asm volatile("s_waitcnt vmcnt(8)" ::: "memory");
        } else {
            asm volatile("s_waitcnt vmcnt(0)" ::: "memory");
        }
        __builtin_amdgcn_s_barrier();
        asm volatile("" ::: "memory");

        const unsigned short* sA = lds + d * 32768;
        const unsigned short* sB = sA + 16384;
#pragma unroll
        for (int ks = 0; ks < 2; ks++) {
            const int qs = ((ks * 4 + fq) ^ (fr & 7)) * 8;
            bf16x8 af[8], bfr[4];
#pragma unroll
            for (int mt = 0; mt < 8; mt++)
                af[mt] = *(const bf16x8*)&sA[(wm * 128 + mt * 16 + fr) * BK + qs];
#pragma unroll
            for (int nt = 0; nt < 4; nt++)
                bfr[nt] = *(const bf16x8*)&sB[(wn + nt * 16 + fr) * BK + qs];
            __builtin_amdgcn_s_setprio(1);
#pragma unroll
            for (int mt = 0; mt < 8; mt++)
#pragma unroll
                for (int nt = 0; nt < 4; nt++)
                    acc[mt][nt] = __builtin_amdgcn_mfma_f32_16x16x32_bf16(
                        af[mt], bfr[nt], acc[mt][nt], 0, 0, 0);
            __builtin_amdgcn_s_setprio(0);
        }
        asm volatile("" ::: "memory");
        __builtin_amdgcn_s_barrier();   // all reads of dbuf d done before next stage into it
    }

    // epilogue: bias + tanh; sole-writer events use plain RMW, dups use atomics
    float bv[4];
#pragma unroll
    for (int ni = 0; ni < 4; ni++) bv[ni] = bias[col0 + wn + ni * 16 + fr];
#pragma unroll
    for (int mi = 0; mi < 8; mi++) {
#pragma unroll
        for (int r = 0; r < 4; r++) {
            const int e = row0 + wm * 128 + mi * 16 + fq * 4 + r;
            const int seq = iseq[e], pos = ipos[e];
            float* hrow = h + ((size_t)seq * ML + pos) * HD + col0 + wn;
            if (dup[e]) {
#pragma unroll
                for (int ni = 0; ni < 4; ni++) {
                    float x = fast_tanh(acc[mi][ni][r] + bv[ni]);
                    atomicAdd(&hrow[ni * 16 + fr], x);
                }
            } else {
#pragma unroll
                for (int ni = 0; ni < 4; ni++) {
                    float x = fast_tanh(acc[mi][ni][r] + bv[ni]);
                    hrow[ni * 16 + fr] += x;
                }
            }
        }
    }
}

// ---- final: h[:, 0, :] = 0 ----
__global__ void zero_first(float* __restrict__ h) {
    const int t = blockIdx.x * 256 + threadIdx.x;
    const int seq = t >> 10, d = t & 1023;
    h[(size_t)seq * ML * HD + d] = 0.0f;
}

extern "C" void kernel_launch(void* const* d_in, const int* in_sizes, int n_in,
                              void* d_out, int out_size, void* d_ws, size_t ws_size,
                              hipStream_t stream) {
    const int* char_i_seq = (const int*)d_in[0];
    const int* char_i_pos = (const int*)d_in[1];
    const int* char_ids   = (const int*)d_in[2];
    const int* grp_i_seq    = (const int*)d_in[3];
    const int* grp_i_first  = (const int*)d_in[4];
    const int* grp_i_second = (const int*)d_in[5];
    const int* grp_i_pos    = (const int*)d_in[6];
    const float* emb = (const float*)d_in[7];
    const float* W   = (const float*)d_in[8];
    const float* b   = (const float*)d_in[9];
    float* h = (float*)d_out;

    unsigned short* WbT = (unsigned short*)d_ws;                            // 4 MB @ 0
    unsigned short* X   = (unsigned short*)((char*)d_ws + (8u << 20));      // 64 MB @ 8M
    int* counts = (int*)((char*)d_ws + (72u << 20));                        // 128 KB
    int* ticket = (int*)((char*)d_ws + (72u << 20) + (1u << 18));           // 128 KB
    int* evlist = (int*)((char*)d_ws + (72u << 20) + (1u << 19));           // 1 MB
    int* gcounts = (int*)((char*)d_ws + (74u << 20));                       // 1.5 MB
    unsigned char* gdup = (unsigned char*)((char*)d_ws + (76u << 20));      // 192 KB

    static bool attr_done = false;
    if (!attr_done) {
        (void)hipFuncSetAttribute((const void*)gemm_scatter,
                                  hipFuncAttributeMaxDynamicSharedMemorySize, LDS_BYTES);
        attr_done = true;
    }

    hipMemsetAsync(counts, 0, NSLOT * sizeof(int), stream);
    hipMemsetAsync(gcounts, 0, (size_t)NLEV * NSLOT * sizeof(int), stream);
    wt_kernel<<<dim3(32, 16), 256, 0, stream>>>(W, WbT);
    char_ticket<<<NEV / 256, 256, 0, stream>>>(char_i_seq, char_i_pos, counts, ticket, evlist);
    char_slot_sum<<<NSLOT, 256, 0, stream>>>(counts, evlist, char_ids, emb, h);
    char_overflow<<<NEV / 128, 256, 0, stream>>>(char_i_seq, char_i_pos, char_ids, ticket, emb, h);
    grp_count<<<(NLEV * NE) / 256, 256, 0, stream>>>(grp_i_seq, grp_i_pos, gcounts);
    grp_dup<<<(NLEV * NE) / 256, 256, 0, stream>>>(grp_i_seq, grp_i_pos, gcounts, gdup);

    for (int lev = 0; lev < NLEV; lev++) {
        const int* iseq = grp_i_seq + lev * NE;
        const int* ifir = grp_i_first + lev * NE;
        const int* isec = grp_i_second + lev * NE;
        const int* ipos = grp_i_pos + lev * NE;
        gather_x<<<NE, 256, 0, stream>>>(h, iseq, ifir, isec, X);
        gemm_scatter<<<dim3(256), 512, LDS_BYTES, stream>>>(X, WbT, b, iseq, ipos,
                                                            gdup + lev * NE, h);
    }
    zero_first<<<32, 256, 0, stream>>>(h);
}

// Round 4
// 1511.258 us; speedup vs baseline: 1.1520x; 1.0444x over previous
//
#include <hip/hip_runtime.h>

#define NS 8
#define ML 4096
#define HD 1024
#define K2 2048
#define NEV 32768
#define NLEV 12
#define NE 16384
#define NSLOT (NS * ML)
#define CAP 8
#define BK 64
#define NT (K2 / BK)          // 32 K-tiles
#define LDS_BYTES 131072      // 2 dbuf x (A 32KB + B 32KB)

typedef __attribute__((ext_vector_type(8))) short bf16x8;
typedef __attribute__((ext_vector_type(4))) float f32x4;

typedef __attribute__((address_space(1))) const void cvoid_g;
typedef __attribute__((address_space(3))) void void_l;

static __device__ __forceinline__ void load_lds_16(const void* g, void* l) {
    __builtin_amdgcn_global_load_lds((cvoid_g*)g, (void_l*)l, 16, 0, 0);
}

static __device__ __forceinline__ unsigned short f2bf(float f) {
    unsigned u = __float_as_uint(f);
    unsigned r = (u + 0x7fffu + ((u >> 16) & 1u)) >> 16;
    return (unsigned short)r;
}

static __device__ __forceinline__ float fast_tanh(float x) {
    return 1.0f - 2.0f / (__expf(2.0f * x) + 1.0f);
}

// ---- W [2048][1024] f32 -> WbT [1024][2048] bf16 (transposed) ----
__global__ void wt_kernel(const float* __restrict__ W, unsigned short* __restrict__ WbT) {
    __shared__ unsigned short tile[64][65];
    const int t = threadIdx.x;
    const int k0 = blockIdx.x * 64;
    const int n0 = blockIdx.y * 64;
#pragma unroll
    for (int i = 0; i < 16; i++) {
        int idx = i * 256 + t;
        int r = idx >> 6, c = idx & 63;
        tile[r][c] = f2bf(W[(size_t)(k0 + r) * HD + n0 + c]);
    }
    __syncthreads();
#pragma unroll
    for (int i = 0; i < 16; i++) {
        int idx = i * 256 + t;
        int r = idx >> 6, c = idx & 63;
        WbT[(size_t)(n0 + r) * K2 + k0 + c] = tile[c][r];
    }
}

// ---- char dedupe pass 1 ----
__global__ void char_ticket(const int* __restrict__ cseq, const int* __restrict__ cpos,
                            int* __restrict__ counts, int* __restrict__ ticket,
                            int* __restrict__ evlist) {
    const int e = blockIdx.x * 256 + threadIdx.x;
    if (e >= NEV) return;
    const int slot = cseq[e] * ML + cpos[e];
    const int t = atomicAdd(&counts[slot], 1);
    ticket[e] = t;
    if (t < CAP) evlist[slot * CAP + t] = e;
}

// ---- char dedupe pass 2: plain store, zero-fills empty slots ----
__global__ void char_slot_sum(const int* __restrict__ counts, const int* __restrict__ evlist,
                              const int* __restrict__ cid, const float* __restrict__ emb,
                              float* __restrict__ h) {
    const int slot = blockIdx.x;
    const int t = threadIdx.x;
    int n = counts[slot];
    if (n > CAP) n = CAP;
    float4 acc = {0.f, 0.f, 0.f, 0.f};
    for (int i = 0; i < n; i++) {
        const int e = evlist[slot * CAP + i];
        const int id = cid[e];
        const float4 v = ((const float4*)(emb + (size_t)id * HD))[t];
        acc.x += v.x; acc.y += v.y; acc.z += v.z; acc.w += v.w;
    }
    ((float4*)(h + (size_t)slot * HD))[t] = acc;
}

// ---- char overflow fallback ----
__global__ void char_overflow(const int* __restrict__ cseq, const int* __restrict__ cpos,
                              const int* __restrict__ cid, const int* __restrict__ ticket,
                              const float* __restrict__ emb, float* __restrict__ h) {
    const int e0 = blockIdx.x * 128;
    const int t = threadIdx.x;
    for (int i = 0; i < 128; i++) {
        const int e = e0 + i;
        if (ticket[e] < CAP) continue;
        const int slot = cseq[e] * ML + cpos[e];
        const int id = cid[e];
        const float4 v = ((const float4*)(emb + (size_t)id * HD))[t];
        float* dst = h + (size_t)slot * HD + t * 4;
        atomicAdd(dst + 0, v.x);
        atomicAdd(dst + 1, v.y);
        atomicAdd(dst + 2, v.z);
        atomicAdd(dst + 3, v.w);
    }
}

// ---- group-event dup detection (all 12 levels at once; indices are static) ----
__global__ void grp_count(const int* __restrict__ iseq, const int* __restrict__ ipos,
                          int* __restrict__ gcounts) {
    const int idx = blockIdx.x * 256 + threadIdx.x;   // 12*16384
    if (idx >= NLEV * NE) return;
    const int lev = idx >> 14;
    atomicAdd(&gcounts[lev * NSLOT + iseq[idx] * ML + ipos[idx]], 1);
}

__global__ void grp_dup(const int* __restrict__ iseq, const int* __restrict__ ipos,
                        const int* __restrict__ gcounts, unsigned char* __restrict__ dup) {
    const int idx = blockIdx.x * 256 + threadIdx.x;
    if (idx >= NLEV * NE) return;
    const int lev = idx >> 14;
    dup[idx] = (gcounts[lev * NSLOT + iseq[idx] * ML + ipos[idx]] > 1) ? 1 : 0;
}

// ---- per-level gather ----
__global__ void gather_x(const float* __restrict__ h, const int* __restrict__ iseq,
                         const int* __restrict__ ifirst, const int* __restrict__ isecond,
                         unsigned short* __restrict__ X) {
    const int e = blockIdx.x;
    const int t = threadIdx.x;
    const int seq = iseq[e], f = ifirst[e], s = isecond[e];
    const float4 a = ((const float4*)(h + ((size_t)seq * ML + f) * HD))[t];
    const float4 b = ((const float4*)(h + ((size_t)seq * ML + s) * HD))[t];
    ushort4 pa, pb;
    pa.x = f2bf(a.x); pa.y = f2bf(a.y); pa.z = f2bf(a.z); pa.w = f2bf(a.w);
    pb.x = f2bf(b.x); pb.y = f2bf(b.y); pb.z = f2bf(b.z); pb.w = f2bf(b.w);
    *(ushort4*)(X + (size_t)e * K2 + t * 4) = pa;
    *(ushort4*)(X + (size_t)e * K2 + HD + t * 4) = pb;
}

// ---- fused GEMM + bias + tanh + dedupe'd scatter ----
// 256x256 tile, BK=64, 8 waves (2M x 4N), 128KB double-buffered LDS.
// 8-phase (4 phases/K-tile) counted-vmcnt schedule (m201-style):
//   P1: read af0(A mh0, 8 b128) + bf0(B nh0, 4) | stage B01(kt+1) | bar | MFMA16 | bar
//   P2: read bf1(B nh1, 4)                      | stage B23       | bar | MFMA16 | vmcnt(4) | bar
//   P3: read af1(A mh1, 8)                      | stage A{0,2}    | bar | MFMA16 | bar
//   P4: (no reads)                              | stage A{1,3}    |       MFMA16 | vmcnt(2) | bar
// Wait derivation (2 loads/unit, issue order B01,B23,A02,A13 per tile):
//   vmcnt(4)@P2-end  -> prev tile's A{1,3} landed (needed by this tile's P3 reads)
//   vmcnt(2)@P4-end  -> next tile's B(all) + A{0,2} landed (needed by next P1 reads)
// In-flight 2..6 loads across every barrier; drain (vmcnt 0) only on the last tile.
__global__ __launch_bounds__(512, 2) void gemm_scatter(
    const unsigned short* __restrict__ X,
    const unsigned short* __restrict__ WbT,
    const float* __restrict__ bias,
    const int* __restrict__ iseq, const int* __restrict__ ipos,
    const unsigned char* __restrict__ dup,
    float* __restrict__ h) {
    extern __shared__ unsigned short lds[];
    const int t = threadIdx.x;
    const int lane = t & 63;
    const int w = t >> 6;            // 0..7
    const int wm = w >> 2;           // 0..1  (M half: 128 rows each)
    const int wn = (w & 3) * 64;     // 0,64,128,192 (N quarter: 64 cols)
    const int fr = lane & 15, fq = lane >> 4;

    // bijective XCD swizzle: 256 blocks, 8 XCDs; blocks on one XCD share a B-panel.
    const int bid = blockIdx.x;
    const int xcd = bid & 7, bix = bid >> 3;
    const int row0 = ((xcd & 1) * 32 + bix) * 256;   // 64 row blocks
    const int col0 = (xcd >> 1) * 256;               // 4 col blocks

    // staging geometry: chunk i covers rows i*64..i*64+63; thread t handles
    // row tr = t>>3 within chunk, 16B-position (t&7), xor-swizzled source sp.
    const int tr = t >> 3;
    const int sp = (t & 7) ^ (tr & 7);
    const unsigned short* Asrc = X + (size_t)(row0 + tr) * K2 + sp * 8;
    const unsigned short* Bsrc = WbT + (size_t)(col0 + tr) * K2 + sp * 8;

    f32x4 acc[8][4];
#pragma unroll
    for (int i = 0; i < 8; i++)
#pragma unroll
        for (int j = 0; j < 4; j++) acc[i][j] = (f32x4){0.f, 0.f, 0.f, 0.f};

    // prologue: stage tile 0 -> buf0 in steady-state unit order B01,B23,A02,A13
    {
        unsigned short* dA = lds;
        unsigned short* dB = lds + 16384;
        load_lds_16(Bsrc + (size_t)(0 * 64) * K2, &dB[(0 * 512 + t) * 8]);
        load_lds_16(Bsrc + (size_t)(1 * 64) * K2, &dB[(1 * 512 + t) * 8]);
        load_lds_16(Bsrc + (size_t)(2 * 64) * K2, &dB[(2 * 512 + t) * 8]);
        load_lds_16(Bsrc + (size_t)(3 * 64) * K2, &dB[(3 * 512 + t) * 8]);
        load_lds_16(Asrc + (size_t)(0 * 64) * K2, &dA[(0 * 512 + t) * 8]);
        load_lds_16(Asrc + (size_t)(2 * 64) * K2, &dA[(2 * 512 + t) * 8]);
        load_lds_16(Asrc + (size_t)(1 * 64) * K2, &dA[(1 * 512 + t) * 8]);
        load_lds_16(Asrc + (size_t)(3 * 64) * K2, &dA[(3 * 512 + t) * 8]);
        asm volatile("s_waitcnt vmcnt(2)" ::: "memory");   // B + A{0,2} landed; A{1,3} in flight
    }
    __builtin_amdgcn_s_barrier();
    asm volatile("" ::: "memory");

    for (int kt = 0; kt < NT; kt++) {
        const int d = kt & 1;
        const unsigned short* sA = lds + d * 32768;
        const unsigned short* sB = sA + 16384;
        unsigned short* nA = lds + (d ^ 1) * 32768;
        unsigned short* nB = nA + 16384;
        const size_t ko = (size_t)(kt + 1) * BK;
        const bool st = (kt + 1 < NT);

        bf16x8 af0[2][4], af1[2][4], bf0[2][2], bf1[2][2];

        // ---------------- P1: af0 + bf0 ; stage B01 ----------------
#pragma unroll
        for (int ks = 0; ks < 2; ks++) {
            const int qs = ((ks * 4 + fq) ^ (fr & 7)) * 8;
#pragma unroll
            for (int mt = 0; mt < 4; mt++)
                af0[ks][mt] = *(const bf16x8*)&sA[(wm * 128 + mt * 16 + fr) * BK + qs];
#pragma unroll
            for (int nt = 0; nt < 2; nt++)
                bf0[ks][nt] = *(const bf16x8*)&sB[(wn + nt * 16 + fr) * BK + qs];
        }
        if (st) {
            load_lds_16(Bsrc + (size_t)(0 * 64) * K2 + ko, &nB[(0 * 512 + t) * 8]);
            load_lds_16(Bsrc + (size_t)(1 * 64) * K2 + ko, &nB[(1 * 512 + t) * 8]);
        }
        asm volatile("" ::: "memory");
        __builtin_amdgcn_s_barrier();
        asm volatile("" ::: "memory");
        __builtin_amdgcn_s_setprio(1);
#pragma unroll
        for (int ks = 0; ks < 2; ks++)
#pragma unroll
            for (int mt = 0; mt < 4; mt++)
#pragma unroll
                for (int nt = 0; nt < 2; nt++)
                    acc[mt][nt] = __builtin_amdgcn_mfma_f32_16x16x32_bf16(
                        af0[ks][mt], bf0[ks][nt], acc[mt][nt], 0, 0, 0);
        __builtin_amdgcn_s_setprio(0);
        asm volatile("" ::: "memory");
        __builtin_amdgcn_s_barrier();
        asm volatile("" ::: "memory");

        // ---------------- P2: bf1 ; stage B23 ; vmcnt(4) ----------------
#pragma unroll
        for (int ks = 0; ks < 2; ks++) {
            const int qs = ((ks * 4 + fq) ^ (fr & 7)) * 8;
#pragma unroll
            for (int nt = 0; nt < 2; nt++)
                bf1[ks][nt] = *(const bf16x8*)&sB[(wn + 32 + nt * 16 + fr) * BK + qs];
        }
        if (st) {
            load_lds_16(Bsrc + (size_t)(2 * 64) * K2 + ko, &nB[(2 * 512 + t) * 8]);
            load_lds_16(Bsrc + (size_t)(3 * 64) * K2 + ko, &nB[(3 * 512 + t) * 8]);
        }
        asm volatile("" ::: "memory");
        __builtin_amdgcn_s_barrier();
        asm volatile("" ::: "memory");
        __builtin_amdgcn_s_setprio(1);
#pragma unroll
        for (int ks = 0; ks < 2; ks++)
#pragma unroll
            for (int mt = 0; mt < 4; mt++)
#pragma unroll
                for (int nt = 0; nt < 2; nt++)
                    acc[mt][2 + nt] = __builtin_amdgcn_mfma_f32_16x16x32_bf16(
                        af0[ks][mt], bf1[ks][nt], acc[mt][2 + nt], 0, 0, 0);
        __builtin_amdgcn_s_setprio(0);
        if (st) { asm volatile("s_waitcnt vmcnt(4)" ::: "memory"); }
        else    { asm volatile("s_waitcnt vmcnt(0)" ::: "memory"); }
        __builtin_amdgcn_s_barrier();
        asm volatile("" ::: "memory");

        // ---------------- P3: af1 ; stage A{0,2} ----------------
#pragma unroll
        for (int ks = 0; ks < 2; ks++) {
            const int qs = ((ks * 4 + fq) ^ (fr & 7)) * 8;
#pragma unroll
            for (int mt = 0; mt < 4; mt++)
                af1[ks][mt] = *(const bf16x8*)&sA[(wm * 128 + 64 + mt * 16 + fr) * BK + qs];
        }
        if (st) {
            load_lds_16(Asrc + (size_t)(0 * 64) * K2 + ko, &nA[(0 * 512 + t) * 8]);
            load_lds_16(Asrc + (size_t)(2 * 64) * K2 + ko, &nA[(2 * 512 + t) * 8]);
        }
        asm volatile("" ::: "memory");
        __builtin_amdgcn_s_barrier();
        asm volatile("" ::: "memory");
        __builtin_amdgcn_s_setprio(1);
#pragma unroll
        for (int ks = 0; ks < 2; ks++)
#pragma unroll
            for (int mt = 0; mt < 4; mt++)
#pragma unroll
                for (int nt = 0; nt < 2; nt++)
                    acc[4 + mt][nt] = __builtin_amdgcn_mfma_f32_16x16x32_bf16(
                        af1[ks][mt], bf0[ks][nt], acc[4 + mt][nt], 0, 0, 0);
        __builtin_amdgcn_s_setprio(0);
        asm volatile("" ::: "memory");
        __builtin_amdgcn_s_barrier();
        asm volatile("" ::: "memory");

        // ---------------- P4: stage A{1,3} ; MFMA ; vmcnt(2) ----------------
        if (st) {
            load_lds_16(Asrc + (size_t)(1 * 64) * K2 + ko, &nA[(1 * 512 + t) * 8]);
            load_lds_16(Asrc + (size_t)(3 * 64) * K2 + ko, &nA[(3 * 512 + t) * 8]);
        }
        asm volatile("" ::: "memory");
        __builtin_amdgcn_s_setprio(1);
#pragma unroll
        for (int ks = 0; ks < 2; ks++)
#pragma unroll
            for (int mt = 0; mt < 4; mt++)
#pragma unroll
                for (int nt = 0; nt < 2; nt++)
                    acc[4 + mt][2 + nt] = __builtin_amdgcn_mfma_f32_16x16x32_bf16(
                        af1[ks][mt], bf1[ks][nt], acc[4 + mt][2 + nt], 0, 0, 0);
        __builtin_amdgcn_s_setprio(0);
        if (st) { asm volatile("s_waitcnt vmcnt(2)" ::: "memory"); }
        else    { asm volatile("s_waitcnt vmcnt(0)" ::: "memory"); }
        __builtin_amdgcn_s_barrier();
        asm volatile("" ::: "memory");
    }

    // epilogue: bias + tanh; sole-writer events use plain RMW, dups use atomics
    float bv[4];
#pragma unroll
    for (int ni = 0; ni < 4; ni++) bv[ni] = bias[col0 + wn + ni * 16 + fr];
#pragma unroll
    for (int mi = 0; mi < 8; mi++) {
#pragma unroll
        for (int r = 0; r < 4; r++) {
            const int e = row0 + wm * 128 + mi * 16 + fq * 4 + r;
            const int seq = iseq[e], pos = ipos[e];
            float* hrow = h + ((size_t)seq * ML + pos) * HD + col0 + wn;
            if (dup[e]) {
#pragma unroll
                for (int ni = 0; ni < 4; ni++) {
                    float x = fast_tanh(acc[mi][ni][r] + bv[ni]);
                    atomicAdd(&hrow[ni * 16 + fr], x);
                }
            } else {
#pragma unroll
                for (int ni = 0; ni < 4; ni++) {
                    float x = fast_tanh(acc[mi][ni][r] + bv[ni]);
                    hrow[ni * 16 + fr] += x;
                }
            }
        }
    }
}

// ---- final: h[:, 0, :] = 0 ----
__global__ void zero_first(float* __restrict__ h) {
    const int t = blockIdx.x * 256 + threadIdx.x;
    const int seq = t >> 10, d = t & 1023;
    h[(size_t)seq * ML * HD + d] = 0.0f;
}

extern "C" void kernel_launch(void* const* d_in, const int* in_sizes, int n_in,
                              void* d_out, int out_size, void* d_ws, size_t ws_size,
                              hipStream_t stream) {
    const int* char_i_seq = (const int*)d_in[0];
    const int* char_i_pos = (const int*)d_in[1];
    const int* char_ids   = (const int*)d_in[2];
    const int* grp_i_seq    = (const int*)d_in[3];
    const int* grp_i_first  = (const int*)d_in[4];
    const int* grp_i_second = (const int*)d_in[5];
    const int* grp_i_pos    = (const int*)d_in[6];
    const float* emb = (const float*)d_in[7];
    const float* W   = (const float*)d_in[8];
    const float* b   = (const float*)d_in[9];
    float* h = (float*)d_out;

    unsigned short* WbT = (unsigned short*)d_ws;                            // 4 MB @ 0
    unsigned short* X   = (unsigned short*)((char*)d_ws + (8u << 20));      // 64 MB @ 8M
    int* counts = (int*)((char*)d_ws + (72u << 20));                        // 128 KB
    int* ticket = (int*)((char*)d_ws + (72u << 20) + (1u << 18));           // 128 KB
    int* evlist = (int*)((char*)d_ws + (72u << 20) + (1u << 19));           // 1 MB
    int* gcounts = (int*)((char*)d_ws + (74u << 20));                       // 1.5 MB
    unsigned char* gdup = (unsigned char*)((char*)d_ws + (76u << 20));      // 192 KB

    static bool attr_done = false;
    if (!attr_done) {
        (void)hipFuncSetAttribute((const void*)gemm_scatter,
                                  hipFuncAttributeMaxDynamicSharedMemorySize, LDS_BYTES);
        attr_done = true;
    }

    hipMemsetAsync(counts, 0, NSLOT * sizeof(int), stream);
    hipMemsetAsync(gcounts, 0, (size_t)NLEV * NSLOT * sizeof(int), stream);
    wt_kernel<<<dim3(32, 16), 256, 0, stream>>>(W, WbT);
    char_ticket<<<NEV / 256, 256, 0, stream>>>(char_i_seq, char_i_pos, counts, ticket, evlist);
    char_slot_sum<<<NSLOT, 256, 0, stream>>>(counts, evlist, char_ids, emb, h);
    char_overflow<<<NEV / 128, 256, 0, stream>>>(char_i_seq, char_i_pos, char_ids, ticket, emb, h);
    grp_count<<<(NLEV * NE) / 256, 256, 0, stream>>>(grp_i_seq, grp_i_pos, gcounts);
    grp_dup<<<(NLEV * NE) / 256, 256, 0, stream>>>(grp_i_seq, grp_i_pos, gcounts, gdup);

    for (int lev = 0; lev < NLEV; lev++) {
        const int* iseq = grp_i_seq + lev * NE;
        const int* ifir = grp_i_first + lev * NE;
        const int* isec = grp_i_second + lev * NE;
        const int* ipos = grp_i_pos + lev * NE;
        gather_x<<<NE, 256, 0, stream>>>(h, iseq, ifir, isec, X);
        gemm_scatter<<<dim3(256), 512, LDS_BYTES, stream>>>(X, WbT, b, iseq, ipos,
                                                            gdup + lev * NE, h);
    }
    zero_first<<<32, 256, 0, stream>>>(h);
}